// Round 2
// baseline (370.369 us; speedup 1.0000x reference)
//
#include <hip/hip_runtime.h>
#include <hip/hip_bf16.h>

typedef __attribute__((ext_vector_type(8))) short bf16x8;
typedef __attribute__((ext_vector_type(4))) float f32x4;

#define K_DIM 64

// Split 8 contiguous fp32 into bf16 hi/lo planes in-register, accumulating
// the exact fp32 sum of squares.
__device__ __forceinline__ void split8(const float* __restrict__ p,
                                       bf16x8& hi, bf16x8& lo, float& ss) {
    #pragma unroll
    for (int j = 0; j < 8; ++j) {
        float v = p[j];
        ss = fmaf(v, v, ss);
        __hip_bfloat16 h = __float2bfloat16(v);
        float hf = __bfloat162float(h);
        __hip_bfloat16 l = __float2bfloat16(v - hf);
        hi[j] = *reinterpret_cast<const short*>(&h);
        lo[j] = *reinterpret_cast<const short*>(&l);
    }
}

// Block = 256 threads = 4 waves. Block tile 64(M) x 64(N); each wave owns a
// 16x64 strip. Split-bf16 MFMA: dot = ahi*bhi + ahi*blo + alo*bhi (lo*lo
// dropped; |err| in sq ~2e-3, budget 0.02).
// Fragment layouts (measured, m89/m91):
//   A: m = lane&15, k = (lane>>4)*8 + j
//   B: n = lane&15, k = (lane>>4)*8 + j
//   D: col = lane&15, row = (lane>>4)*4 + reg
// Row norms: lanes sharing l16 jointly hold a row's K=64 -> xor-16 + xor-32
// butterfly gives the full ||.||^2 in every participating lane.
__global__ __launch_bounds__(256) void rbf_fused(
    const float* __restrict__ x, const float* __restrict__ c,
    const float* __restrict__ ls, float* __restrict__ out, int N)
{
    const int wave = threadIdx.x >> 6;
    const int lane = threadIdx.x & 63;
    const int quad = lane >> 4;
    const int l16  = lane & 15;

    const int m_base = (blockIdx.y << 6) + (wave << 4);
    const int n_base = blockIdx.x << 6;

    // ---- A fragments (row am, k-chunks quad*8 and 32+quad*8) + x norms ----
    const int am = m_base + l16;
    const float* xp = x + (size_t)am * K_DIM;
    bf16x8 ahi0, alo0, ahi1, alo1;
    float ssx = 0.f;
    split8(xp + quad * 8,      ahi0, alo0, ssx);
    split8(xp + 32 + quad * 8, ahi1, alo1, ssx);
    ssx += __shfl_xor(ssx, 16, 64);
    ssx += __shfl_xor(ssx, 32, 64);
    // lane j now holds ||x_{m_base+(j&15)}||^2; fetch the 4 rows this lane
    // writes in D-layout (row = quad*4 + r).
    float nxr[4];
    #pragma unroll
    for (int r = 0; r < 4; ++r)
        nxr[r] = __shfl(ssx, quad * 4 + r, 64);

    #pragma unroll
    for (int nt = 0; nt < 4; ++nt) {
        const int n = n_base + nt * 16 + l16;   // B-frag col == D-layout col
        const float* cp = c + (size_t)n * K_DIM;
        bf16x8 bhi0, blo0, bhi1, blo1;
        float ssc = 0.f;
        split8(cp + quad * 8,      bhi0, blo0, ssc);
        split8(cp + 32 + quad * 8, bhi1, blo1, ssc);
        ssc += __shfl_xor(ssc, 16, 64);
        ssc += __shfl_xor(ssc, 32, 64);        // ||c_n||^2 for this lane's n

        f32x4 acc = {0.f, 0.f, 0.f, 0.f};
        acc = __builtin_amdgcn_mfma_f32_16x16x32_bf16(ahi0, bhi0, acc, 0, 0, 0);
        acc = __builtin_amdgcn_mfma_f32_16x16x32_bf16(ahi1, bhi1, acc, 0, 0, 0);
        acc = __builtin_amdgcn_mfma_f32_16x16x32_bf16(ahi0, blo0, acc, 0, 0, 0);
        acc = __builtin_amdgcn_mfma_f32_16x16x32_bf16(ahi1, blo1, acc, 0, 0, 0);
        acc = __builtin_amdgcn_mfma_f32_16x16x32_bf16(alo0, bhi0, acc, 0, 0, 0);
        acc = __builtin_amdgcn_mfma_f32_16x16x32_bf16(alo1, bhi1, acc, 0, 0, 0);

        const float invv = __expf(-2.0f * ls[n]);
        #pragma unroll
        for (int r = 0; r < 4; ++r) {
            const int row = m_base + quad * 4 + r;
            float sq = fmaxf(nxr[r] + ssc - 2.0f * acc[r], 0.f);
            out[(size_t)row * N + n] = __expf(-sq * invv);
        }
    }
}

extern "C" void kernel_launch(void* const* d_in, const int* in_sizes, int n_in,
                              void* d_out, int out_size, void* d_ws, size_t ws_size,
                              hipStream_t stream) {
    const float* x  = (const float*)d_in[0];   // [M,64]
    const float* c  = (const float*)d_in[1];   // [N,64]
    const float* ls = (const float*)d_in[2];   // [N]
    float* out = (float*)d_out;                // [M,N]

    const int M = in_sizes[0] / K_DIM;   // 16384
    const int N = in_sizes[2];           // 4096

    rbf_fused<<<dim3(N / 64, M / 64), 256, 0, stream>>>(x, c, ls, out, N);
}